// Round 3
// baseline (207.073 us; speedup 1.0000x reference)
//
#include <hip/hip_runtime.h>
#include <stdint.h>

typedef unsigned short u16;
typedef __attribute__((ext_vector_type(8))) short short8;   // 8 bf16 = 4 VGPRs (MFMA A/B frag)
typedef __attribute__((ext_vector_type(4))) float f32x4;    // 16x16 MFMA C/D frag
typedef __attribute__((ext_vector_type(16))) float f32x16;  // 32x32 MFMA C/D frag

#define LOG2E 1.4426950408889634f
#define NT 8192
#define DH 256

// ---- workspace layout (u16 element offsets) ----
#define QH     0
#define KH     2097152
#define VTB    4194304          // V transposed: [256][8192]
#define OPARTB 6291456          // 8 x [8192][256] bf16 unnormalized partial O (32 MB)
// temps (dead after k_qkv; deliberately overlap OPARTB region):
#define XH0 6291456
#define XL0 8388608
#define XH1 10485760
#define XL1 12582912
#define XH2 14680064
#define XL2 16777216
#define WQH 18874368
#define WQL 18939904
#define WKH 19005440
#define WKL 19070976
#define WVH 19136512
#define WVL 19202048
// fp32 region (float element offsets), after OPARTB:
#define MPART_F 11534336        // 8 x [8192] per-split softmax base m0
#define LPART_F 11599872        // 8 x [8192] per-split denom

__device__ __forceinline__ u16 f2bf(float f) {
  union { float f; uint32_t u; } c; c.f = f;
  uint32_t u = c.u;
  return (u16)((u + 0x7fffu + ((u >> 16) & 1)) >> 16);   // RNE
}
__device__ __forceinline__ float bf2f(u16 h) {
  union { uint32_t u; float f; } c; c.u = ((uint32_t)h) << 16;
  return c.f;
}

// XOR swizzle for LDS rows of 32 16B-units (512B rows)
__device__ __forceinline__ int swz32(int u, int h) {    // h = row hash (3 bits)
  return (u & 24) | ((u & 7) ^ (h & 7));
}

__device__ __forceinline__ f32x4 mfma16(short8 a, short8 b, f32x4 c) {
  return __builtin_amdgcn_mfma_f32_16x16x32_bf16(a, b, c, 0, 0, 0);
}
__device__ __forceinline__ f32x16 mfma32(short8 a, short8 b, f32x16 c) {
  return __builtin_amdgcn_mfma_f32_32x32x16_bf16(a, b, c, 0, 0, 0);
}

// async global->LDS, 16B per lane; LDS dest is wave-uniform base + lane*16
__device__ __forceinline__ void gl_lds16(const u16* g, u16* l) {
  __builtin_amdgcn_global_load_lds(
      (const __attribute__((address_space(1))) uint32_t*)g,
      (__attribute__((address_space(3))) uint32_t*)l, 16, 0, 0);
}

// ---------------- kernel 1: fp32 -> hi/lo bf16 split ----------------
__global__ __launch_bounds__(256) void k_convert(
    const float* __restrict__ x1, const float* __restrict__ x2, const float* __restrict__ x3,
    const float* __restrict__ wq, const float* __restrict__ wk, const float* __restrict__ wv,
    u16* __restrict__ wsu) {
  int b = blockIdx.x;
  const float* src; u16 *dh, *dl; int bl;
  if (b < 1024)      { src = x1; dh = wsu + XH0; dl = wsu + XL0; bl = b; }
  else if (b < 2048) { src = x2; dh = wsu + XH1; dl = wsu + XL1; bl = b - 1024; }
  else if (b < 3072) { src = x3; dh = wsu + XH2; dl = wsu + XL2; bl = b - 2048; }
  else if (b < 3104) { src = wq; dh = wsu + WQH; dl = wsu + WQL; bl = b - 3072; }
  else if (b < 3136) { src = wk; dh = wsu + WKH; dl = wsu + WKL; bl = b - 3104; }
  else               { src = wv; dh = wsu + WVH; dl = wsu + WVL; bl = b - 3136; }
  int i = (bl * 256 + threadIdx.x) * 8;
  f32x4 a = *(const f32x4*)(src + i);
  f32x4 c = *(const f32x4*)(src + i + 4);
  short8 rh, rl;
  float v[8] = {a[0], a[1], a[2], a[3], c[0], c[1], c[2], c[3]};
#pragma unroll
  for (int j = 0; j < 8; j++) {
    u16 h = f2bf(v[j]);
    rh[j] = (short)h;
    rl[j] = (short)f2bf(v[j] - bf2f(h));
  }
  *(short8*)(dh + i) = rh;
  *(short8*)(dl + i) = rl;
}

// ---------------- kernel 2: QKV projection v5 — A-stationary + DMA-staged B ----------------
// (unchanged; produces bitwise-same Q/K/Vt)
__global__ __launch_bounds__(256) void k_qkv(
    u16* __restrict__ wsu,
    const float* __restrict__ bq, const float* __restrict__ bk, const float* __restrict__ bv) {
  __shared__ u16 sAh[32 * 256];   // 16 KB
  __shared__ u16 sAl[32 * 256];   // 16 KB
  __shared__ u16 sBh[32 * 256];   // 16 KB (current col-group, hi)
  __shared__ u16 sBl[32 * 256];   // 16 KB (lo)
  int bx = blockIdx.x;
  int mid = bx >> 8;
  int t = bx & 255;
  const u16 *Ah, *Al, *Bh, *Bl; u16 *O; const float* bias;
  int rowA0, colBase, ldO, biasRow;
  if (mid == 0) {
    Ah = wsu + XH0; Al = wsu + XL0; Bh = wsu + WQH; Bl = wsu + WQL;
    O = wsu + QH; bias = bq; biasRow = 0; ldO = 256;
    rowA0 = t * 32; colBase = 0;
  } else if (mid == 1) {
    Ah = wsu + XH1; Al = wsu + XL1; Bh = wsu + WKH; Bl = wsu + WKL;
    O = wsu + KH; bias = bk; biasRow = 0; ldO = 256;
    rowA0 = t * 32; colBase = 0;
  } else {
    Ah = wsu + WVH; Al = wsu + WVL; Bh = wsu + XH2; Bl = wsu + XL2;
    O = wsu + VTB; bias = bv; biasRow = 1; ldO = 8192;
    rowA0 = (t & 7) * 32; colBase = (t >> 3) * 256;
  }

  int tid = threadIdx.x;
  int lane = tid & 63, wave = tid >> 6;
  int n = lane & 15, quad = lane >> 4;
  int wm = wave >> 1, wn = wave & 1;

  // stage A once (plain contiguous loads)
#pragma unroll
  for (int i = 0; i < 4; i++) {
    int L = i * 256 + tid;
    int row = L >> 5, u = L & 31;
    short8 vh = *(const short8*)(Ah + (size_t)(rowA0 + row) * 256 + u * 8);
    short8 vl = *(const short8*)(Al + (size_t)(rowA0 + row) * 256 + u * 8);
    *(short8*)(&sAh[row * 256 + swz32(u, row) * 8]) = vh;
    *(short8*)(&sAl[row * 256 + swz32(u, row) * 8]) = vl;
  }

  int brow0 = wave * 2 + (lane >> 5);
  int bgu = (lane & 24) | ((lane & 7) ^ (brow0 & 7));

#pragma unroll
  for (int i = 0; i < 4; i++) {
    gl_lds16(Bh + (size_t)(colBase + i * 8 + brow0) * 256 + bgu * 8, &sBh[i * 2048 + wave * 512]);
    gl_lds16(Bl + (size_t)(colBase + i * 8 + brow0) * 256 + bgu * 8, &sBl[i * 2048 + wave * 512]);
  }

#pragma unroll 1
  for (int g = 0; g < 8; g++) {
    __syncthreads();

    int colg = colBase + g * 32 + wn * 16 + n;
    f32x4 acc = {0.f, 0.f, 0.f, 0.f};
#pragma unroll
    for (int kk = 0; kk < 8; kk++) {
      int ra = wm * 16 + n;
      int rbB = wn * 16 + n;
      short8 ah = *(const short8*)(&sAh[ra * 256 + swz32(kk * 4 + quad, ra) * 8]);
      short8 al = *(const short8*)(&sAl[ra * 256 + swz32(kk * 4 + quad, ra) * 8]);
      short8 bh = *(const short8*)(&sBh[rbB * 256 + swz32(kk * 4 + quad, rbB) * 8]);
      short8 bl = *(const short8*)(&sBl[rbB * 256 + swz32(kk * 4 + quad, rbB) * 8]);
      acc = mfma16(ah, bh, acc);
      acc = mfma16(ah, bl, acc);
      acc = mfma16(al, bh, acc);
    }

    if (g < 7) {
      __syncthreads();
      int b0 = colBase + (g + 1) * 32;
#pragma unroll
      for (int i = 0; i < 4; i++) {
        gl_lds16(Bh + (size_t)(b0 + i * 8 + brow0) * 256 + bgu * 8, &sBh[i * 2048 + wave * 512]);
        gl_lds16(Bl + (size_t)(b0 + i * 8 + brow0) * 256 + bgu * 8, &sBl[i * 2048 + wave * 512]);
      }
    }

    float bcol = biasRow ? 0.0f : bias[colg];
#pragma unroll
    for (int r = 0; r < 4; r++) {
      int rowg = rowA0 + wm * 16 + quad * 4 + r;
      float bb = biasRow ? bias[rowg] : bcol;
      O[(size_t)rowg * ldO + colg] = f2bf(acc[r] + bb);
    }
  }
}

// ---------------- kernel 3: flash attention v10 — PV-lag software pipeline ----------------
// R2 lesson: conflicts halved (17M->8.6M) but time -2% -> conflicts off critical path; no
// pipe >60% busy -> phase-serialization (QK^T chain -> softmax -> PV in lockstep) is the
// limiter. v10: compute PV(it-1) inside iter it, same basic block as QK^T(it) — independent
// MFMA streams interleave, softmax(it) overlaps PV issue. V DMA shifted one tile later than
// K DMA so the existing 2xK+2xV 64KB double-buffer still has no read/write slot overlap in
// any inter-barrier window; one barrier/iter preserved. pb frags (8 regs) carry across the
// barrier. it=0: pb=0 and PV A-operand pointed at valid K tile (uninit LDS could encode NaN;
// NaN*0=NaN) -> contributes exactly 0, keeps the block branch-free. Bitwise-same output.
__global__ __launch_bounds__(256, 2) void k_flash(
    const u16* __restrict__ wsu, u16* __restrict__ opart, float* __restrict__ wsf) {
  __shared__ u16 smem[32768];   // 64 KB: [0]=K0 [8192]=K1 [16384]=V0 [24576]=V1 (u16 idx)

  int qb = blockIdx.x >> 3, sp = blockIdx.x & 7;   // split -> XCD pinning
  int tid = threadIdx.x, lane = tid & 63, wave = tid >> 6;
  int key = lane & 31;       // lane's S^T output column-owner row / d_local in PV
  int h = lane >> 5;         // k-half
  const u16* Qp = wsu + QH;
  const u16* Kp = wsu + KH;
  const u16* Vp = wsu + VTB;

  int rowQ0 = qb * 128 + wave * 32;

  // Q B-frags (col=lane&31=qrow, k=h*8+e), 16 chunks of K=16: 64 VGPR
  short8 qf[16];
#pragma unroll
  for (int kk = 0; kk < 16; kk++)
    qf[kk] = *(const short8*)(Qp + (size_t)(rowQ0 + key) * 256 + kk * 16 + h * 8);

  // iter-invariant LDS read byte-offsets
  int koff[4];               // K: row=key (512B), unit su = 8*(kk>>2) | ((2*(kk&3)+h)^(key&7))
#pragma unroll
  for (int m = 0; m < 4; m++)
    koff[m] = key * 512 + 16 * ((2 * m + h) ^ (key & 7));
  int voff[2];               // V: row=d (64B), unit (2c+h)^((d>>1)&3); (d>>1)&3 == (key>>1)&3
#pragma unroll
  for (int c = 0; c < 2; c++)
    voff[c] = key * 64 + 16 * ((2 * c + h) ^ ((key >> 1) & 3));

  // staging lane geometry (source pre-swizzled, LDS dest linear — m173 pattern)
  int krow0 = wave * 2 + h;                           // K rows: i*8 + krow0, hash = krow0&7
  int kgu = (lane & 24) | ((lane & 7) ^ (krow0 & 7));
  int vd_base = wave * 16 + (lane >> 2);              // V d = i*64 + vd_base
  int vgu = (lane & 3) ^ ((lane >> 3) & 3);           // hash = (d>>1)&3 = (lane>>3)&3

  int key00 = sp * 1024;

  // preload K tile 0 only (V(0) DMA issues inside iter 0 — V stream lags K by one tile)
#pragma unroll
  for (int i = 0; i < 4; i++) {
    gl_lds16(Kp + (size_t)(key00 + i * 8 + krow0) * 256 + kgu * 8,
             &smem[i * 2048 + wave * 512]);
  }

  f32x16 o[8];               // O^T accumulators: 8 d-tiles of 32, col=qrow
#pragma unroll
  for (int dt = 0; dt < 8; dt++)
#pragma unroll
    for (int r = 0; r < 16; r++) o[dt][r] = 0.f;
  float negm0 = 0.f, lcur = 0.f;

  union PB { uint32_t u[4]; short8 s8; };
  PB pb0, pb1;               // carried P frags (pb(it-1) consumed at iter it)
#pragma unroll
  for (int j = 0; j < 4; j++) { pb0.u[j] = 0u; pb1.u[j] = 0u; }

#pragma unroll 1
  for (int it = 0; it < 32; it++) {
    __syncthreads();   // DMAs issued last iter drained (K(it), V(it-1)); all waves off reused slots
    int cur = it & 1;
    const u16* sKc = &smem[cur * 8192];
    if (it + 1 < 32) {
      int k1 = key00 + (it + 1) * 32;
#pragma unroll
      for (int i = 0; i < 4; i++)
        gl_lds16(Kp + (size_t)(k1 + i * 8 + krow0) * 256 + kgu * 8,
                 &smem[(cur ^ 1) * 8192 + i * 2048 + wave * 512]);
    }
    {
      int kv = key00 + it * 32;   // V(it) -> vbuf[cur] (read by PV(it) next iter)
#pragma unroll
      for (int i = 0; i < 4; i++)
        gl_lds16(Vp + (size_t)(i * 64 + vd_base) * 8192 + kv + vgu * 8,
                 &smem[16384 + cur * 8192 + i * 2048 + wave * 512]);
    }

    // PV(it-1) A-operand source: vbuf[cur^1]; at it=0 point at K tile (finite data) x pb=0
    const u16* sVp = (it > 0) ? &smem[16384 + (cur ^ 1) * 8192] : sKc;

    // S^T[key][qrow] = K @ Q^T  +  PV(it-1): independent MFMA streams, one basic block
    f32x16 s;
#pragma unroll
    for (int r = 0; r < 16; r++) s[r] = 0.f;
    __builtin_amdgcn_s_setprio(1);
#pragma unroll
    for (int kk = 0; kk < 16; kk++) {
      short8 kf = *(const short8*)((const char*)sKc + koff[kk & 3] + 128 * (kk >> 2));
      s = mfma32(kf, qf[kk], s);
    }
#pragma unroll
    for (int dt = 0; dt < 8; dt++) {
      short8 v0 = *(const short8*)((const char*)sVp + voff[0] + dt * 2048);
      o[dt] = mfma32(v0, pb0.s8, o[dt]);
    }
#pragma unroll
    for (int dt = 0; dt < 8; dt++) {
      short8 v1 = *(const short8*)((const char*)sVp + voff[1] + dt * 2048);
      o[dt] = mfma32(v1, pb1.s8, o[dt]);
    }
    __builtin_amdgcn_s_setprio(0);

    // fixed softmax base from tile 0 (covers all 32 keys: 16 in-lane + partner half)
    if (it == 0) {
      float mv = s[0];
#pragma unroll
      for (int r = 1; r < 16; r++) mv = fmaxf(mv, s[r]);
      mv = fmaxf(mv, __shfl_xor(mv, 32));
      negm0 = -mv * LOG2E;
    }

    // p = exp2(s*log2e + negm0); pack adjacent-key pairs to bf16 in-register.
    uint32_t c8[8];
#pragma unroll
    for (int j = 0; j < 8; j++) {
      float x0 = fminf(fmaf(s[2 * j],     LOG2E, negm0), 110.f);
      float x1 = fminf(fmaf(s[2 * j + 1], LOG2E, negm0), 110.f);
      float p0 = exp2f(x0);
      float p1 = exp2f(x1);
      lcur += p0 + p1;
      asm("v_cvt_pk_bf16_f32 %0, %1, %2" : "=v"(c8[j]) : "v"(p0), "v"(p1));
    }
    // permlane32_swap: (w0,w2) = swap(c0,c2) etc. -> B-frag words per k-chunk
    uint32_t w0a = c8[0], w2a = c8[2], w1a = c8[1], w3a = c8[3];
    asm("v_permlane32_swap_b32 %0, %1" : "+v"(w0a), "+v"(w2a));
    asm("v_permlane32_swap_b32 %0, %1" : "+v"(w1a), "+v"(w3a));
    uint32_t w0b = c8[4], w2b = c8[6], w1b = c8[5], w3b = c8[7];
    asm("v_permlane32_swap_b32 %0, %1" : "+v"(w0b), "+v"(w2b));
    asm("v_permlane32_swap_b32 %0, %1" : "+v"(w1b), "+v"(w3b));
    pb0.u[0] = w0a; pb0.u[1] = w1a; pb0.u[2] = w2a; pb0.u[3] = w3a;
    pb1.u[0] = w0b; pb1.u[1] = w1b; pb1.u[2] = w2b; pb1.u[3] = w3b;
  }

  // epilogue: drain V(31) DMA, then final PV(31)
  __syncthreads();
  {
    const u16* sVp = &smem[16384 + 8192];   // slot 31&1 = 1
    __builtin_amdgcn_s_setprio(1);
#pragma unroll
    for (int dt = 0; dt < 8; dt++) {
      short8 v0 = *(const short8*)((const char*)sVp + voff[0] + dt * 2048);
      o[dt] = mfma32(v0, pb0.s8, o[dt]);
    }
#pragma unroll
    for (int dt = 0; dt < 8; dt++) {
      short8 v1 = *(const short8*)((const char*)sVp + voff[1] + dt * 2048);
      o[dt] = mfma32(v1, pb1.s8, o[dt]);
    }
    __builtin_amdgcn_s_setprio(0);
  }

  // combine the two key-halves of the denominator
  lcur += __shfl_xor(lcur, 32);

  // ---- epilogue: transpose O^T -> row-major bf16 partials via freed LDS ----
  __syncthreads();   // all waves done with PV(31) reads (tb overlays the V1 region)
  u16* tb = &smem[wave * 8192];   // [32 rows][256 d], 16B-unit swizzle u ^= (row&7)
#pragma unroll
  for (int dt = 0; dt < 8; dt++)
#pragma unroll
    for (int j = 0; j < 4; j++) {
      uint32_t a, b;
      asm("v_cvt_pk_bf16_f32 %0, %1, %2" : "=v"(a) : "v"(o[dt][4 * j + 0]), "v"(o[dt][4 * j + 1]));
      asm("v_cvt_pk_bf16_f32 %0, %1, %2" : "=v"(b) : "v"(o[dt][4 * j + 2]), "v"(o[dt][4 * j + 3]));
      int u16i = (dt * 4 + j) ^ (key & 7);
      uint2 val; val.x = a; val.y = b;
      *(uint2*)((char*)tb + key * 512 + u16i * 16 + h * 8) = val;
    }
  // wave-local read-back + coalesced store
  u16* op = opart + (size_t)sp * (NT * DH);
#pragma unroll
  for (int c2i = 0; c2i < 16; c2i++) {
    int rl = c2i * 2 + h;            // local row 0..31
    int uu = lane & 31;              // 16B unit (8 d's)
    short8 vv = *(const short8*)((const char*)tb + rl * 512 + ((uu ^ (rl & 7)) * 16));
    *(short8*)(op + (size_t)(rowQ0 + rl) * 256 + uu * 8) = vv;
  }

  // stats (one lane per q-row)
  if (lane < 32) {
    int row = rowQ0 + key;
    wsf[MPART_F + sp * NT + row] = negm0 * -0.6931471805599453f;
    wsf[LPART_F + sp * NT + row] = lcur;
  }
}

// ---------------- kernel 4: combine 8 splits ----------------
__global__ __launch_bounds__(256) void k_combine(
    const u16* __restrict__ opart, const float* __restrict__ wsf, float* __restrict__ out) {
  int gid = blockIdx.x * 256 + threadIdx.x;
  int row = gid >> 6, cg = gid & 63;
  float m[8], l[8];
#pragma unroll
  for (int s = 0; s < 8; s++) {
    m[s] = wsf[MPART_F + s * NT + row];
    l[s] = wsf[LPART_F + s * NT + row];
  }
  float ms = m[0];
#pragma unroll
  for (int s = 1; s < 8; s++) ms = fmaxf(ms, m[s]);
  float denom = 0.f;
  float acc[4] = {0.f, 0.f, 0.f, 0.f};
#pragma unroll
  for (int s = 0; s < 8; s++) {
    float w = exp2f((m[s] - ms) * LOG2E);
    denom += w * l[s];
    const u16* pp = opart + ((size_t)s * NT + row) * 256 + cg * 4;
    uint2 v = *(const uint2*)pp;
    acc[0] += w * bf2f((u16)(v.x & 0xffff));
    acc[1] += w * bf2f((u16)(v.x >> 16));
    acc[2] += w * bf2f((u16)(v.y & 0xffff));
    acc[3] += w * bf2f((u16)(v.y >> 16));
  }
  float inv = 1.0f / denom;
  f32x4 r = {acc[0] * inv, acc[1] * inv, acc[2] * inv, acc[3] * inv};
  *(f32x4*)(out + (size_t)row * 256 + cg * 4) = r;
}

extern "C" void kernel_launch(void* const* d_in, const int* in_sizes, int n_in,
                              void* d_out, int out_size, void* d_ws, size_t ws_size,
                              hipStream_t stream) {
  const float* x1 = (const float*)d_in[0];
  const float* x2 = (const float*)d_in[1];
  const float* x3 = (const float*)d_in[2];
  const float* Wq = (const float*)d_in[3];
  const float* bq = (const float*)d_in[4];
  const float* Wk = (const float*)d_in[5];
  const float* bk = (const float*)d_in[6];
  const float* Wv = (const float*)d_in[7];
  const float* bv = (const float*)d_in[8];
  u16* wsu = (u16*)d_ws;
  float* wsf = (float*)d_ws;
  float* out = (float*)d_out;

  k_convert<<<dim3(3168), dim3(256), 0, stream>>>(x1, x2, x3, Wq, Wk, Wv, wsu);
  k_qkv<<<dim3(768), dim3(256), 0, stream>>>(wsu, bq, bk, bv);
  k_flash<<<dim3(512), dim3(256), 0, stream>>>(wsu, wsu + OPARTB, wsf);
  k_combine<<<dim3(2048), dim3(256), 0, stream>>>(wsu + OPARTB, wsf, out);
}

// Round 6
// 196.570 us; speedup vs baseline: 1.0534x; 1.0534x over previous
//
#include <hip/hip_runtime.h>
#include <stdint.h>

typedef unsigned short u16;
typedef __attribute__((ext_vector_type(8))) short short8;   // 8 bf16 = 4 VGPRs (MFMA A/B frag)
typedef __attribute__((ext_vector_type(4))) float f32x4;    // 16x16 MFMA C/D frag
typedef __attribute__((ext_vector_type(16))) float f32x16;  // 32x32 MFMA C/D frag

#define LOG2E 1.4426950408889634f
#define NT 8192
#define DH 256

// ---- workspace layout (u16 element offsets) ----
#define QH     0
#define KH     2097152
#define VTB    4194304          // V transposed: [256][8192]
#define OPARTB 6291456          // 8 x [8192][256] bf16 unnormalized partial O (32 MB)
// fp32 region (float element offsets), after OPARTB:
#define MPART_F 11534336        // 8 x [8192] per-split softmax base m0
#define LPART_F 11599872        // 8 x [8192] per-split denom
// (hi/lo temp regions + k_convert are GONE: conversion is inlined into k_qkv2)

__device__ __forceinline__ u16 f2bf(float f) {
  union { float f; uint32_t u; } c; c.f = f;
  uint32_t u = c.u;
  return (u16)((u + 0x7fffu + ((u >> 16) & 1)) >> 16);   // RNE
}
__device__ __forceinline__ float bf2f(u16 h) {
  union { uint32_t u; float f; } c; c.u = ((uint32_t)h) << 16;
  return c.f;
}

// XOR swizzle for LDS rows of 32 16B-units (512B rows)
__device__ __forceinline__ int swz32(int u, int h) {    // h = row hash (3 bits)
  return (u & 24) | ((u & 7) ^ (h & 7));
}

__device__ __forceinline__ f32x4 mfma16(short8 a, short8 b, f32x4 c) {
  return __builtin_amdgcn_mfma_f32_16x16x32_bf16(a, b, c, 0, 0, 0);
}
__device__ __forceinline__ f32x16 mfma32(short8 a, short8 b, f32x16 c) {
  return __builtin_amdgcn_mfma_f32_32x32x16_bf16(a, b, c, 0, 0, 0);
}

// async global->LDS, 16B per lane; LDS dest is wave-uniform base + lane*16
__device__ __forceinline__ void gl_lds16(const u16* g, u16* l) {
  __builtin_amdgcn_global_load_lds(
      (const __attribute__((address_space(1))) uint32_t*)g,
      (__attribute__((address_space(3))) uint32_t*)l, 16, 0, 0);
}

// convert 8 fp32 -> hi/lo bf16 short8 (bitwise-identical to the old k_convert)
__device__ __forceinline__ void cvt8(const float* v, short8& vh, short8& vl) {
#pragma unroll
  for (int j = 0; j < 8; j++) {
    u16 hh = f2bf(v[j]);
    vh[j] = (short)hh;
    vl[j] = (short)f2bf(v[j] - bf2f(hh));
  }
}

// ---------------- kernel 1: QKV projection with INLINE fp32->hi/lo convert ----------------
// R5's phase Q, verified numerically (absmax 0.03125), now standalone: the 78 MB hi/lo temp
// round-trip and the separate k_convert dispatch are eliminated. 512 blocks x 2 items:
//   item0: bid<256 -> Q (x1 @ Wq^T + bq); else K (x2 @ Wk^T + bk). 8 col-groups.
//   item1: Vt (Wv stationary, x3 cols staged), 512 half-width items (4 groups).
// A and B staged from fp32 via regs -> LDS in the exact image the old DMA produced:
// LDS[row][swz32(u,row)] = src[row][u] -> identical MFMA term order -> bitwise-same Q/K/Vt.
__global__ __launch_bounds__(256) void k_qkv2(
    const float* __restrict__ x1, const float* __restrict__ x2, const float* __restrict__ x3,
    const float* __restrict__ wqp, const float* __restrict__ bqp,
    const float* __restrict__ wkp, const float* __restrict__ bkp,
    const float* __restrict__ wvp, const float* __restrict__ bvp,
    u16* __restrict__ wsu) {
  __shared__ u16 smem[32768];   // 64 KB: sAh/sAl/sBh/sBl 16 KB each
  u16* sAh = smem;
  u16* sAl = smem + 8192;
  u16* sBh = smem + 16384;
  u16* sBl = smem + 24576;

  int bid = blockIdx.x, tid = threadIdx.x;
  int lane = tid & 63, wave = tid >> 6;
  int n = lane & 15, quad = lane >> 4;
  int wm = wave >> 1, wn = wave & 1;

#pragma unroll 1
  for (int item = 0; item < 2; item++) {
    const float *Asrc, *Bsrc, *bias; u16* O;
    int rowA0, colBase, ldO, biasRow, nG;
    if (item == 0) {
      if (bid < 256) { Asrc = x1; Bsrc = wqp; bias = bqp; O = wsu + QH; rowA0 = bid * 32; }
      else           { Asrc = x2; Bsrc = wkp; bias = bkp; O = wsu + KH; rowA0 = (bid - 256) * 32; }
      colBase = 0; ldO = 256; biasRow = 0; nG = 8;
    } else {
      Asrc = wvp; Bsrc = x3; bias = bvp; O = wsu + VTB;
      rowA0 = (bid & 7) * 32; colBase = (bid >> 3) * 128; ldO = 8192; biasRow = 1; nG = 4;
    }

    __syncthreads();   // all waves done with smem from previous item

    // stage A: fp32 -> hi/lo LDS (same image as the old DMA path)
#pragma unroll
    for (int i = 0; i < 4; i++) {
      int L = i * 256 + tid, row = L >> 5, u = L & 31;
      const float* p = Asrc + (size_t)(rowA0 + row) * 256 + u * 8;
      f32x4 a = *(const f32x4*)p, c = *(const f32x4*)(p + 4);
      float v[8] = {a[0], a[1], a[2], a[3], c[0], c[1], c[2], c[3]};
      short8 vh, vl; cvt8(v, vh, vl);
      *(short8*)(&sAh[row * 256 + swz32(u, row) * 8]) = vh;
      *(short8*)(&sAl[row * 256 + swz32(u, row) * 8]) = vl;
    }

    // load + stage B(0)
    f32x4 pf[8];
#pragma unroll
    for (int i = 0; i < 4; i++) {
      int L = i * 256 + tid, row = L >> 5, u = L & 31;
      const float* p = Bsrc + (size_t)(colBase + row) * 256 + u * 8;
      pf[i * 2] = *(const f32x4*)p; pf[i * 2 + 1] = *(const f32x4*)(p + 4);
    }
#pragma unroll
    for (int i = 0; i < 4; i++) {
      int L = i * 256 + tid, row = L >> 5, u = L & 31;
      float v[8] = {pf[i*2][0], pf[i*2][1], pf[i*2][2], pf[i*2][3],
                    pf[i*2+1][0], pf[i*2+1][1], pf[i*2+1][2], pf[i*2+1][3]};
      short8 vh, vl; cvt8(v, vh, vl);
      *(short8*)(&sBh[row * 256 + swz32(u, row) * 8]) = vh;
      *(short8*)(&sBl[row * 256 + swz32(u, row) * 8]) = vl;
    }

#pragma unroll 1
    for (int g = 0; g < nG; g++) {
      __syncthreads();   // B(g) writes visible; prior reads done

      // prefetch B(g+1) fp32 into regs (latency hides under MFMA)
      if (g + 1 < nG) {
        int b0 = colBase + (g + 1) * 32;
#pragma unroll
        for (int i = 0; i < 4; i++) {
          int L = i * 256 + tid, row = L >> 5, u = L & 31;
          const float* p = Bsrc + (size_t)(b0 + row) * 256 + u * 8;
          pf[i * 2] = *(const f32x4*)p; pf[i * 2 + 1] = *(const f32x4*)(p + 4);
        }
      }

      int colg = colBase + g * 32 + wn * 16 + n;
      f32x4 acc = {0.f, 0.f, 0.f, 0.f};
#pragma unroll
      for (int kk = 0; kk < 8; kk++) {
        int ra = wm * 16 + n, rbB = wn * 16 + n;
        short8 ah = *(const short8*)(&sAh[ra * 256 + swz32(kk * 4 + quad, ra) * 8]);
        short8 al = *(const short8*)(&sAl[ra * 256 + swz32(kk * 4 + quad, ra) * 8]);
        short8 bh = *(const short8*)(&sBh[rbB * 256 + swz32(kk * 4 + quad, rbB) * 8]);
        short8 bl = *(const short8*)(&sBl[rbB * 256 + swz32(kk * 4 + quad, rbB) * 8]);
        acc = mfma16(ah, bh, acc);
        acc = mfma16(ah, bl, acc);
        acc = mfma16(al, bh, acc);
      }

      __syncthreads();   // all waves done reading B(g)
      if (g + 1 < nG) {
#pragma unroll
        for (int i = 0; i < 4; i++) {
          int L = i * 256 + tid, row = L >> 5, u = L & 31;
          float v[8] = {pf[i*2][0], pf[i*2][1], pf[i*2][2], pf[i*2][3],
                        pf[i*2+1][0], pf[i*2+1][1], pf[i*2+1][2], pf[i*2+1][3]};
          short8 vh, vl; cvt8(v, vh, vl);
          *(short8*)(&sBh[row * 256 + swz32(u, row) * 8]) = vh;
          *(short8*)(&sBl[row * 256 + swz32(u, row) * 8]) = vl;
        }
      }

      float bcol = biasRow ? 0.0f : bias[colg];
#pragma unroll
      for (int r = 0; r < 4; r++) {
        int rowg = rowA0 + wm * 16 + quad * 4 + r;
        float bb = biasRow ? bias[rowg] : bcol;
        O[(size_t)rowg * ldO + colg] = f2bf(acc[r] + bb);
      }
    }
  }
}

// ---------------- kernel 2: flash attention v10 (PV-lag pipeline, R3-verified) ----------------
__global__ __launch_bounds__(256, 2) void k_flash(
    const u16* __restrict__ wsu, u16* __restrict__ opart, float* __restrict__ wsf) {
  __shared__ u16 smem[32768];   // 64 KB: [0]=K0 [8192]=K1 [16384]=V0 [24576]=V1 (u16 idx)

  int qb = blockIdx.x >> 3, sp = blockIdx.x & 7;   // split -> XCD pinning
  int tid = threadIdx.x, lane = tid & 63, wave = tid >> 6;
  int key = lane & 31;
  int h = lane >> 5;
  const u16* Qp = wsu + QH;
  const u16* Kp = wsu + KH;
  const u16* Vp = wsu + VTB;

  int rowQ0 = qb * 128 + wave * 32;

  short8 qf[16];
#pragma unroll
  for (int kk = 0; kk < 16; kk++)
    qf[kk] = *(const short8*)(Qp + (size_t)(rowQ0 + key) * 256 + kk * 16 + h * 8);

  int koff[4];
#pragma unroll
  for (int m = 0; m < 4; m++)
    koff[m] = key * 512 + 16 * ((2 * m + h) ^ (key & 7));
  int voff[2];
#pragma unroll
  for (int c = 0; c < 2; c++)
    voff[c] = key * 64 + 16 * ((2 * c + h) ^ ((key >> 1) & 3));

  int krow0 = wave * 2 + h;
  int kgu = (lane & 24) | ((lane & 7) ^ (krow0 & 7));
  int vd_base = wave * 16 + (lane >> 2);
  int vgu = (lane & 3) ^ ((lane >> 3) & 3);

  int key00 = sp * 1024;

  // preload K tile 0 only (V lags K by one tile)
#pragma unroll
  for (int i = 0; i < 4; i++) {
    gl_lds16(Kp + (size_t)(key00 + i * 8 + krow0) * 256 + kgu * 8,
             &smem[i * 2048 + wave * 512]);
  }

  f32x16 o[8];
#pragma unroll
  for (int dt = 0; dt < 8; dt++)
#pragma unroll
    for (int r = 0; r < 16; r++) o[dt][r] = 0.f;
  float negm0 = 0.f, lcur = 0.f;

  union PB { uint32_t u[4]; short8 s8; };
  PB pb0, pb1;
#pragma unroll
  for (int j = 0; j < 4; j++) { pb0.u[j] = 0u; pb1.u[j] = 0u; }

#pragma unroll 1
  for (int it = 0; it < 32; it++) {
    __syncthreads();   // K(it), V(it-1) DMA drained; all waves off reused slots
    int cur = it & 1;
    const u16* sKc = &smem[cur * 8192];
    if (it + 1 < 32) {
      int k1 = key00 + (it + 1) * 32;
#pragma unroll
      for (int i = 0; i < 4; i++)
        gl_lds16(Kp + (size_t)(k1 + i * 8 + krow0) * 256 + kgu * 8,
                 &smem[(cur ^ 1) * 8192 + i * 2048 + wave * 512]);
    }
    {
      int kv = key00 + it * 32;   // V(it) -> vbuf[cur] (read by PV(it) next iter)
#pragma unroll
      for (int i = 0; i < 4; i++)
        gl_lds16(Vp + (size_t)(i * 64 + vd_base) * 8192 + kv + vgu * 8,
                 &smem[16384 + cur * 8192 + i * 2048 + wave * 512]);
    }

    const u16* sVp = (it > 0) ? &smem[16384 + (cur ^ 1) * 8192] : sKc;

    f32x16 s;
#pragma unroll
    for (int r = 0; r < 16; r++) s[r] = 0.f;
    __builtin_amdgcn_s_setprio(1);
#pragma unroll
    for (int kk = 0; kk < 16; kk++) {
      short8 kf = *(const short8*)((const char*)sKc + koff[kk & 3] + 128 * (kk >> 2));
      s = mfma32(kf, qf[kk], s);
    }
#pragma unroll
    for (int dt = 0; dt < 8; dt++) {
      short8 v0 = *(const short8*)((const char*)sVp + voff[0] + dt * 2048);
      o[dt] = mfma32(v0, pb0.s8, o[dt]);
    }
#pragma unroll
    for (int dt = 0; dt < 8; dt++) {
      short8 v1 = *(const short8*)((const char*)sVp + voff[1] + dt * 2048);
      o[dt] = mfma32(v1, pb1.s8, o[dt]);
    }
    __builtin_amdgcn_s_setprio(0);

    if (it == 0) {
      float mv = s[0];
#pragma unroll
      for (int r = 1; r < 16; r++) mv = fmaxf(mv, s[r]);
      mv = fmaxf(mv, __shfl_xor(mv, 32));
      negm0 = -mv * LOG2E;
    }

    uint32_t c8[8];
#pragma unroll
    for (int j = 0; j < 8; j++) {
      float x0 = fminf(fmaf(s[2 * j],     LOG2E, negm0), 110.f);
      float x1 = fminf(fmaf(s[2 * j + 1], LOG2E, negm0), 110.f);
      float p0 = exp2f(x0);
      float p1 = exp2f(x1);
      lcur += p0 + p1;
      asm("v_cvt_pk_bf16_f32 %0, %1, %2" : "=v"(c8[j]) : "v"(p0), "v"(p1));
    }
    uint32_t w0a = c8[0], w2a = c8[2], w1a = c8[1], w3a = c8[3];
    asm("v_permlane32_swap_b32 %0, %1" : "+v"(w0a), "+v"(w2a));
    asm("v_permlane32_swap_b32 %0, %1" : "+v"(w1a), "+v"(w3a));
    uint32_t w0b = c8[4], w2b = c8[6], w1b = c8[5], w3b = c8[7];
    asm("v_permlane32_swap_b32 %0, %1" : "+v"(w0b), "+v"(w2b));
    asm("v_permlane32_swap_b32 %0, %1" : "+v"(w1b), "+v"(w3b));
    pb0.u[0] = w0a; pb0.u[1] = w1a; pb0.u[2] = w2a; pb0.u[3] = w3a;
    pb1.u[0] = w0b; pb1.u[1] = w1b; pb1.u[2] = w2b; pb1.u[3] = w3b;
  }

  // drain V(31) DMA, final PV(31)
  __syncthreads();
  {
    const u16* sVp = &smem[16384 + 8192];
    __builtin_amdgcn_s_setprio(1);
#pragma unroll
    for (int dt = 0; dt < 8; dt++) {
      short8 v0 = *(const short8*)((const char*)sVp + voff[0] + dt * 2048);
      o[dt] = mfma32(v0, pb0.s8, o[dt]);
    }
#pragma unroll
    for (int dt = 0; dt < 8; dt++) {
      short8 v1 = *(const short8*)((const char*)sVp + voff[1] + dt * 2048);
      o[dt] = mfma32(v1, pb1.s8, o[dt]);
    }
    __builtin_amdgcn_s_setprio(0);
  }

  lcur += __shfl_xor(lcur, 32);

  // transpose O^T -> row-major bf16 partials via freed LDS
  __syncthreads();
  u16* tb = &smem[wave * 8192];
#pragma unroll
  for (int dt = 0; dt < 8; dt++)
#pragma unroll
    for (int j = 0; j < 4; j++) {
      uint32_t a, b;
      asm("v_cvt_pk_bf16_f32 %0, %1, %2" : "=v"(a) : "v"(o[dt][4 * j + 0]), "v"(o[dt][4 * j + 1]));
      asm("v_cvt_pk_bf16_f32 %0, %1, %2" : "=v"(b) : "v"(o[dt][4 * j + 2]), "v"(o[dt][4 * j + 3]));
      int u16i = (dt * 4 + j) ^ (key & 7);
      uint2 val; val.x = a; val.y = b;
      *(uint2*)((char*)tb + key * 512 + u16i * 16 + h * 8) = val;
    }
  u16* op = opart + (size_t)sp * (NT * DH);
#pragma unroll
  for (int c2i = 0; c2i < 16; c2i++) {
    int rl = c2i * 2 + h;
    int uu = lane & 31;
    short8 vv = *(const short8*)((const char*)tb + rl * 512 + ((uu ^ (rl & 7)) * 16));
    *(short8*)(op + (size_t)(rowQ0 + rl) * 256 + uu * 8) = vv;
  }

  if (lane < 32) {
    int row = rowQ0 + key;
    wsf[MPART_F + sp * NT + row] = negm0 * -0.6931471805599453f;
    wsf[LPART_F + sp * NT + row] = lcur;
  }
}

// ---------------- kernel 3: combine 8 splits ----------------
__global__ __launch_bounds__(256) void k_combine(
    const u16* __restrict__ opart, const float* __restrict__ wsf, float* __restrict__ out) {
  int gid = blockIdx.x * 256 + threadIdx.x;
  int row = gid >> 6, cg = gid & 63;
  float m[8], l[8];
#pragma unroll
  for (int s = 0; s < 8; s++) {
    m[s] = wsf[MPART_F + s * NT + row];
    l[s] = wsf[LPART_F + s * NT + row];
  }
  float ms = m[0];
#pragma unroll
  for (int s = 1; s < 8; s++) ms = fmaxf(ms, m[s]);
  float denom = 0.f;
  float acc[4] = {0.f, 0.f, 0.f, 0.f};
#pragma unroll
  for (int s = 0; s < 8; s++) {
    float w = exp2f((m[s] - ms) * LOG2E);
    denom += w * l[s];
    const u16* pp = opart + ((size_t)s * NT + row) * 256 + cg * 4;
    uint2 v = *(const uint2*)pp;
    acc[0] += w * bf2f((u16)(v.x & 0xffff));
    acc[1] += w * bf2f((u16)(v.x >> 16));
    acc[2] += w * bf2f((u16)(v.y & 0xffff));
    acc[3] += w * bf2f((u16)(v.y >> 16));
  }
  float inv = 1.0f / denom;
  f32x4 r = {acc[0] * inv, acc[1] * inv, acc[2] * inv, acc[3] * inv};
  *(f32x4*)(out + (size_t)row * 256 + cg * 4) = r;
}

extern "C" void kernel_launch(void* const* d_in, const int* in_sizes, int n_in,
                              void* d_out, int out_size, void* d_ws, size_t ws_size,
                              hipStream_t stream) {
  const float* x1 = (const float*)d_in[0];
  const float* x2 = (const float*)d_in[1];
  const float* x3 = (const float*)d_in[2];
  const float* Wq = (const float*)d_in[3];
  const float* bq = (const float*)d_in[4];
  const float* Wk = (const float*)d_in[5];
  const float* bk = (const float*)d_in[6];
  const float* Wv = (const float*)d_in[7];
  const float* bv = (const float*)d_in[8];
  u16* wsu = (u16*)d_ws;
  float* wsf = (float*)d_ws;
  float* out = (float*)d_out;

  k_qkv2<<<dim3(512), dim3(256), 0, stream>>>(x1, x2, x3, Wq, bq, Wk, bk, Wv, bv, wsu);
  k_flash<<<dim3(512), dim3(256), 0, stream>>>(wsu, wsu + OPARTB, wsf);
  k_combine<<<dim3(2048), dim3(256), 0, stream>>>(wsu + OPARTB, wsf, out);
}